// Round 17
// baseline (1759.418 us; speedup 1.0000x reference)
//
#include <hip/hip_runtime.h>
#include <math.h>

#define NN 10000
#define NE 160000
#define H  128
#define LD 8

typedef unsigned short ushort_t;
typedef short bf16x8 __attribute__((ext_vector_type(8)));
typedef float f32x4 __attribute__((ext_vector_type(4)));

__device__ __forceinline__ float silu_f(float x){ return x / (1.0f + expf(-x)); }
__device__ __forceinline__ float4 f4z(){ return make_float4(0.f,0.f,0.f,0.f); }

__device__ __forceinline__ void fma4(float4& acc, float s, const float4 w){
    acc.x = fmaf(s, w.x, acc.x);
    acc.y = fmaf(s, w.y, acc.y);
    acc.z = fmaf(s, w.z, acc.z);
    acc.w = fmaf(s, w.w, acc.w);
}

__device__ __forceinline__ float4 silu4(float4 a, float4 b){
    return make_float4(silu_f(a.x+b.x), silu_f(a.y+b.y), silu_f(a.z+b.z), silu_f(a.w+b.w));
}

__device__ __forceinline__ ushort_t f2bf(float f){
    union { float f; unsigned int u; } x; x.f = f;
    unsigned int r = x.u + 0x7FFFu + ((x.u >> 16) & 1u);
    return (ushort_t)(r >> 16);
}
__device__ __forceinline__ unsigned int pack2bf(float a, float b){
    return (unsigned int)f2bf(a) | ((unsigned int)f2bf(b) << 16);
}
__device__ __forceinline__ float bf2f_hi(unsigned int u){
    union { unsigned int u; float f; } x; x.u = u & 0xffff0000u; return x.f;
}
__device__ __forceinline__ float bf2f_lo(unsigned int u){
    union { unsigned int u; float f; } x; x.u = u << 16; return x.f;
}

// ---------------------------------------------------------------------------
// Prep: transpose GEMM weights to bf16 W^T[n][k]; cast ef to bf16.
// ---------------------------------------------------------------------------
__global__ void k_prepw(const float* __restrict__ Wq, const float* __restrict__ Wk,
                        const float* __restrict__ Wv, const float* __restrict__ W_vec,
                        const float* __restrict__ Wtrg, const float* __restrict__ Wsrc,
                        const float* __restrict__ Wdk, const float* __restrict__ Wdv,
                        const float* __restrict__ Ws,
                        ushort_t* __restrict__ wqkvT, ushort_t* __restrict__ wvecT,
                        ushort_t* __restrict__ wdkT, ushort_t* __restrict__ wdvT,
                        ushort_t* __restrict__ wsT){
    int i = blockIdx.x * 256 + threadIdx.x;          // 0 .. 196607
    int n = i >> 7, kk = i & 127;
    if (n < 384){                                    // wqkvT
        float v;
        if (n < 128)      v = Wq[kk*128 + n];
        else if (n < 256) v = Wk[kk*128 + (n-128)];
        else              v = Wv[kk*128 + (n-256)];
        wqkvT[n*128 + kk] = f2bf(v);
    } else if (n < 1024){                            // wvecT (640 rows)
        int m = n - 384;
        float v;
        if (m < 384)      v = W_vec[kk*384 + m];
        else if (m < 512) v = Wtrg[kk*128 + (m-384)];
        else              v = Wsrc[kk*128 + (m-512)];
        wvecT[m*128 + kk] = f2bf(v);
    } else if (n < 1152){
        int m = n - 1024;
        wdkT[m*128 + kk] = f2bf(Wdk[kk*128 + m]);
    } else if (n < 1280){
        int m = n - 1152;
        wdvT[m*128 + kk] = f2bf(Wdv[kk*128 + m]);
    } else if (n < 1536){
        int m = n - 1280;
        wsT[m*128 + kk] = f2bf(Ws[kk*256 + m]);
    }
}

__global__ void k_ef2bf(const float* __restrict__ ef, ushort_t* __restrict__ ef_bf){
    size_t i = (size_t)blockIdx.x * 256 + threadIdx.x;   // over E*H/8
    const float4* s = (const float4*)ef;
    float4 a = s[2*i], b = s[2*i+1];
    uint4 u;
    u.x = pack2bf(a.x, a.y); u.y = pack2bf(a.z, a.w);
    u.z = pack2bf(b.x, b.y); u.w = pack2bf(b.z, b.w);
    ((uint4*)ef_bf)[i] = u;
}

// ---------------------------------------------------------------------------
// Sort edges by receiver: histogram -> exclusive scan -> rank scatter.
// ---------------------------------------------------------------------------
__global__ void k_hist(const int* __restrict__ rcv, int* __restrict__ cnt){
    int e = blockIdx.x * 256 + threadIdx.x;
    if (e < NE) atomicAdd(&cnt[rcv[e]], 1);
}

__global__ __launch_bounds__(256) void k_scan(const int* __restrict__ cnt, int* __restrict__ offs){
    __shared__ int part[256];
    const int t = threadIdx.x;
    const int CH = 40;
    int loc[CH];
    int base = t * CH;
    int lsum = 0;
    if (base < NN){
        #pragma unroll
        for (int i = 0; i < CH; i++){ loc[i] = cnt[base + i]; lsum += loc[i]; }
    }
    part[t] = lsum;
    __syncthreads();
    for (int off = 1; off < 256; off <<= 1){
        int v = (t >= off) ? part[t - off] : 0;
        __syncthreads();
        part[t] += v;
        __syncthreads();
    }
    int ex = part[t] - lsum;
    if (base < NN){
        int run = ex;
        #pragma unroll
        for (int i = 0; i < CH; i++){ offs[base + i] = run; run += loc[i]; }
    }
    if (t == 255) offs[NN] = part[255];
}

__global__ void k_scatter(const int* __restrict__ rcv, const int* __restrict__ offs,
                          int* __restrict__ cnt2, int* __restrict__ eidx){
    int e = blockIdx.x * 256 + threadIdx.x;
    if (e < NE){
        int r = rcv[e];
        int p = atomicAdd(&cnt2[r], 1);
        eidx[offs[r] + p] = e;
    }
}

// ---------------------------------------------------------------------------
// K1a: LayerNorm -> x_bf (bf16); vec = vf*vln_w -> vec_bf (bf16).
// ---------------------------------------------------------------------------
__global__ __launch_bounds__(128) void node_ln(
    const float* __restrict__ nf, const float* __restrict__ vf,
    const float* __restrict__ ln_s, const float* __restrict__ ln_b,
    const float* __restrict__ vlnw,
    ushort_t* __restrict__ x_bf, ushort_t* __restrict__ vec_bf)
{
    const int n = blockIdx.x, h = threadIdx.x;
    __shared__ float red[4];
    float xv = nf[(size_t)n*H + h];
    float s1 = xv, s2 = xv*xv;
    #pragma unroll
    for (int o = 32; o >= 1; o >>= 1){
        s1 += __shfl_xor(s1, o, 64);
        s2 += __shfl_xor(s2, o, 64);
    }
    const int wid = h >> 6;
    if ((h & 63) == 0){ red[wid] = s1; red[2+wid] = s2; }
    __syncthreads();
    float mean = (red[0] + red[1]) * (1.0f/H);
    float var  = (red[2] + red[3]) * (1.0f/H) - mean*mean;
    float x = (xv - mean) * rsqrtf(var + 1e-5f) * ln_s[h] + ln_b[h];
    x_bf[(size_t)n*H + h] = f2bf(x);
    float w = vlnw[h];
    #pragma unroll
    for (int l = 0; l < LD; l++){
        size_t i = ((size_t)n*LD + l)*H + h;
        vec_bf[i] = f2bf(vf[i] * w);
    }
}

// ---------------------------------------------------------------------------
// K1b (MFMA): q (f32), k/v (bf16) = x_bf @ wqkvT^T + bias.
// ---------------------------------------------------------------------------
__global__ __launch_bounds__(256) void node_qkv(
    const ushort_t* __restrict__ x_bf, const ushort_t* __restrict__ wqkvT,
    const float* __restrict__ bq, const float* __restrict__ bk, const float* __restrict__ bv,
    float* __restrict__ q, ushort_t* __restrict__ k_bf, ushort_t* __restrict__ v_bf)
{
    const int tid  = threadIdx.x;
    const int lane = tid & 63;
    const int m0   = (tid >> 6) * 16;
    const int e0   = blockIdx.x * 64;

    const int mrow = lane & 15;
    const int kblk = lane >> 4;

    f32x4 acc[24];
    #pragma unroll
    for (int nt = 0; nt < 24; nt++) acc[nt] = (f32x4)(0.f);

    int arow = e0 + m0 + mrow; if (arow >= NN) arow = NN-1;
    const ushort_t* Arow = x_bf + (size_t)arow*H + kblk*8;
    const ushort_t* wb   = wqkvT + (size_t)mrow*H + kblk*8;

    #pragma unroll
    for (int ks = 0; ks < 4; ks++){
        bf16x8 a = *(const bf16x8*)(Arow + ks*32);
        #pragma unroll
        for (int nt = 0; nt < 24; nt++){
            bf16x8 b8 = *(const bf16x8*)(wb + (size_t)nt*16*H + ks*32);
            acc[nt] = __builtin_amdgcn_mfma_f32_16x16x32_bf16(a, b8, acc[nt], 0, 0, 0);
        }
    }
    #pragma unroll
    for (int t = 0; t < 8; t++){
        int col = t*16 + mrow;
        float bb = bq[col];
        #pragma unroll
        for (int r = 0; r < 4; r++){
            int row = e0 + m0 + kblk*4 + r;
            if (row < NN) q[(size_t)row*H + col] = acc[t][r] + bb;
        }
    }
    #pragma unroll
    for (int t = 0; t < 8; t++){
        int col = t*16 + mrow;
        float bb = bk[col];
        #pragma unroll
        for (int r = 0; r < 4; r++){
            int row = e0 + m0 + kblk*4 + r;
            if (row < NN) k_bf[(size_t)row*H + col] = f2bf(acc[8+t][r] + bb);
        }
    }
    #pragma unroll
    for (int t = 0; t < 8; t++){
        int col = t*16 + mrow;
        float bb = bv[col];
        #pragma unroll
        for (int r = 0; r < 4; r++){
            int row = e0 + m0 + kblk*4 + r;
            if (row < NN) v_bf[(size_t)row*H + col] = f2bf(acc[16+t][r] + bb);
        }
    }
}

// ---------------------------------------------------------------------------
// K1c (MFMA): V5 = vec_bf @ wvecT^T, N=640; fused vdot + bf16 outputs
// (vec3 / Vt / Vs in row layout).
// ---------------------------------------------------------------------------
__global__ __launch_bounds__(256) void node_vec(
    const ushort_t* __restrict__ vec_bf, const ushort_t* __restrict__ wvecT,
    float* __restrict__ vdot, ushort_t* __restrict__ vec3,
    ushort_t* __restrict__ Vt, ushort_t* __restrict__ Vs)
{
    __shared__ ushort_t st_s[64][136];

    const int tid  = threadIdx.x;
    const int lane = tid & 63;
    const int wv   = tid >> 6;
    const int m0   = wv * 16;
    const size_t r0 = (size_t)blockIdx.x * 64;       // global row = node*8+l

    const int mrow = lane & 15;
    const int kblk = lane >> 4;

    f32x4 acc[40];
    #pragma unroll
    for (int nt = 0; nt < 40; nt++) acc[nt] = (f32x4)(0.f);

    const ushort_t* Arow = vec_bf + (r0 + m0 + mrow)*H + kblk*8;
    const ushort_t* wb   = wvecT + (size_t)mrow*H + kblk*8;

    #pragma unroll
    for (int ks = 0; ks < 4; ks++){
        bf16x8 a = *(const bf16x8*)(Arow + ks*32);
        #pragma unroll
        for (int nt = 0; nt < 40; nt++){
            bf16x8 b8 = *(const bf16x8*)(wb + (size_t)nt*16*H + ks*32);
            acc[nt] = __builtin_amdgcn_mfma_f32_16x16x32_bf16(a, b8, acc[nt], 0, 0, 0);
        }
    }

    #pragma unroll
    for (int t = 0; t < 8; t++){
        float p = acc[t][0]*acc[t+8][0] + acc[t][1]*acc[t+8][1]
                + acc[t][2]*acc[t+8][2] + acc[t][3]*acc[t+8][3];
        p += __shfl_xor(p, 16, 64);                  // kblk 0<->1, 2<->3
        if ((kblk & 1) == 0){
            int node = (int)(r0 >> 3) + wv*2 + (kblk >> 1);
            vdot[(size_t)node*H + t*16 + mrow] = p;
        }
    }

    ushort_t* outs[3] = {vec3, Vt, Vs};
    #pragma unroll
    for (int g = 0; g < 3; g++){
        __syncthreads();
        #pragma unroll
        for (int t = 0; t < 8; t++){
            int coln = t*16 + mrow;
            int lr = m0 + kblk*4;
            st_s[lr+0][coln] = f2bf(acc[16+g*8+t][0]);
            st_s[lr+1][coln] = f2bf(acc[16+g*8+t][1]);
            st_s[lr+2][coln] = f2bf(acc[16+g*8+t][2]);
            st_s[lr+3][coln] = f2bf(acc[16+g*8+t][3]);
        }
        __syncthreads();
        const int rr = tid >> 2, qq = tid & 3;
        uint4* dst = (uint4*)&outs[g][(r0 + rr)*H + qq*32];
        const uint4* src = (const uint4*)&st_s[rr][qq*32];
        dst[0] = src[0]; dst[1] = src[1]; dst[2] = src[2]; dst[3] = src[3];
    }
}

// ---------------------------------------------------------------------------
// K2 (MFMA): dk/dv = silu(ef@Wdk/dv + b), attention epilogue -> vj (bf16).
// Natural edge order; k/v gathered as bf16 (halved bytes).
// ---------------------------------------------------------------------------
__global__ __launch_bounds__(256) void edge_attn(
    const ushort_t* __restrict__ ef_bf,
    const ushort_t* __restrict__ wdkT, const float* __restrict__ bdk,
    const ushort_t* __restrict__ wdvT, const float* __restrict__ bdv,
    const int* __restrict__ snd, const int* __restrict__ rcv,
    const float* __restrict__ dist,
    const float* __restrict__ q, const ushort_t* __restrict__ k_bf,
    const ushort_t* __restrict__ v_bf,
    ushort_t* __restrict__ vj)
{
    __shared__ ushort_t dk_s[64][136];
    __shared__ ushort_t dv_s[64][136];

    const int tid  = threadIdx.x;
    const int lane = tid & 63;
    const int m0   = (tid >> 6) * 16;
    const size_t e0 = (size_t)blockIdx.x * 64;

    const int mrow = lane & 15;
    const int kblk = lane >> 4;

    f32x4 accK[8], accV[8];
    #pragma unroll
    for (int nt = 0; nt < 8; nt++){ accK[nt] = (f32x4)(0.f); accV[nt] = (f32x4)(0.f); }

    const ushort_t* Arow = ef_bf + (e0 + m0 + mrow)*H + kblk*8;
    const ushort_t* wkb  = wdkT + (size_t)mrow*H + kblk*8;
    const ushort_t* wvb  = wdvT + (size_t)mrow*H + kblk*8;

    #pragma unroll
    for (int ks = 0; ks < 4; ks++){
        bf16x8 a = *(const bf16x8*)(Arow + ks*32);
        #pragma unroll
        for (int nt = 0; nt < 8; nt++){
            bf16x8 bk8 = *(const bf16x8*)(wkb + (size_t)nt*16*H + ks*32);
            accK[nt] = __builtin_amdgcn_mfma_f32_16x16x32_bf16(a, bk8, accK[nt], 0, 0, 0);
            bf16x8 bv8 = *(const bf16x8*)(wvb + (size_t)nt*16*H + ks*32);
            accV[nt] = __builtin_amdgcn_mfma_f32_16x16x32_bf16(a, bv8, accV[nt], 0, 0, 0);
        }
    }

    const int lrow = m0 + 4*kblk;
    #pragma unroll
    for (int nt = 0; nt < 8; nt++){
        int coln = nt*16 + mrow;
        float bkn = bdk[coln], bvn = bdv[coln];
        #pragma unroll
        for (int r = 0; r < 4; r++){
            dk_s[lrow + r][coln] = f2bf(silu_f(accK[nt][r] + bkn));
            dv_s[lrow + r][coln] = f2bf(silu_f(accV[nt][r] + bvn));
        }
    }
    __syncthreads();

    const int r  = tid >> 2, cq = tid & 3;
    const size_t e = e0 + r;
    const int s  = snd[e], rr = rcv[e];
    const float d = dist[e];
    const float cut = (d < 5.0f) ? 0.5f*(cosf(d*0.6283185307179586f) + 1.0f) : 0.0f;
    const float*    qrow = q    + (size_t)rr*H + cq*32;
    const ushort_t* krow = k_bf + (size_t)s*H + cq*32;
    const ushort_t* vrow = v_bf + (size_t)s*H + cq*32;
    ushort_t* vjrow = vj + e*H + cq*32;

    #pragma unroll
    for (int hh = 0; hh < 2; hh++){
        const int c0 = hh*16;
        float p = 0.f;
        #pragma unroll
        for (int j = 0; j < 4; j++){
            float4 q4 = *(const float4*)(qrow + c0 + 4*j);
            uint2 ku = *(const uint2*)(krow + c0 + 4*j);
            uint2 du = *(const uint2*)&dk_s[r][cq*32 + c0 + 4*j];
            p += q4.x*bf2f_lo(ku.x)*bf2f_lo(du.x) + q4.y*bf2f_hi(ku.x)*bf2f_hi(du.x)
               + q4.z*bf2f_lo(ku.y)*bf2f_lo(du.y) + q4.w*bf2f_hi(ku.y)*bf2f_hi(du.y);
        }
        float attn = silu_f(p) * cut;
        #pragma unroll
        for (int j = 0; j < 4; j++){
            uint2 vu = *(const uint2*)(vrow + c0 + 4*j);
            uint2 du = *(const uint2*)&dv_s[r][cq*32 + c0 + 4*j];
            uint2 u;
            u.x = pack2bf(bf2f_lo(vu.x)*bf2f_lo(du.x)*attn,
                          bf2f_hi(vu.x)*bf2f_hi(du.x)*attn);
            u.y = pack2bf(bf2f_lo(vu.y)*bf2f_lo(du.y)*attn,
                          bf2f_hi(vu.y)*bf2f_hi(du.y)*attn);
            *(uint2*)(vjrow + c0 + 4*j) = u;
        }
    }
}

// ---------------------------------------------------------------------------
// K3 (MFMA): s12 = silu(vj@Ws + bs) [E,256] bf16.
// ---------------------------------------------------------------------------
__global__ __launch_bounds__(256) void edge_s(
    const ushort_t* __restrict__ vj, const ushort_t* __restrict__ wsT,
    const float* __restrict__ bs, ushort_t* __restrict__ s12)
{
    __shared__ ushort_t s_s[64][264];

    const int tid  = threadIdx.x;
    const int lane = tid & 63;
    const int m0   = (tid >> 6) * 16;
    const size_t e0 = (size_t)blockIdx.x * 64;

    const int mrow = lane & 15;
    const int kblk = lane >> 4;

    f32x4 acc[16];
    #pragma unroll
    for (int nt = 0; nt < 16; nt++) acc[nt] = (f32x4)(0.f);

    const ushort_t* Arow = vj + (e0 + m0 + mrow)*H + kblk*8;
    const ushort_t* wb   = wsT + (size_t)mrow*H + kblk*8;

    #pragma unroll
    for (int ks = 0; ks < 4; ks++){
        bf16x8 a = *(const bf16x8*)(Arow + ks*32);
        #pragma unroll
        for (int nt = 0; nt < 16; nt++){
            bf16x8 b8 = *(const bf16x8*)(wb + (size_t)nt*16*H + ks*32);
            acc[nt] = __builtin_amdgcn_mfma_f32_16x16x32_bf16(a, b8, acc[nt], 0, 0, 0);
        }
    }

    const int lrow = m0 + 4*kblk;
    #pragma unroll
    for (int nt = 0; nt < 16; nt++){
        int coln = nt*16 + mrow;
        float bb = bs[coln];
        #pragma unroll
        for (int r = 0; r < 4; r++)
            s_s[lrow + r][coln] = f2bf(silu_f(acc[nt][r] + bb));
    }
    __syncthreads();

    const int r = tid >> 2, cq = tid & 3;
    const uint4* srcp = (const uint4*)&s_s[r][cq*64];
    uint4* dstp = (uint4*)&s12[(e0 + r)*256 + cq*64];
    #pragma unroll
    for (int j = 0; j < 8; j++) dstp[j] = srcp[j];
}

// ---------------------------------------------------------------------------
// K4 (f32 GEMV — proven-precision path): df = silu(ef@Wf+bf) * w_dot with
// w_dot = (A.B) - a*b*(2-|d|^2), A=Vt[rcv], B=Vs[snd] (bf16).
// 32 edges/block, column-HALF per blockIdx.y. LDS ~51KB -> 3 blocks/CU.
// e_s read as float4 (4 k/read, FMA order preserved -> bit-identical).
// Receiver-sorted edge order.
// ---------------------------------------------------------------------------
__global__ __launch_bounds__(256) void edge_df(
    const float* __restrict__ ef, const float* __restrict__ Wf, const float* __restrict__ bf_,
    const int* __restrict__ eidx,
    const int* __restrict__ snd, const int* __restrict__ rcv,
    const float* __restrict__ dij,
    const ushort_t* __restrict__ Vt, const ushort_t* __restrict__ Vs,
    float* __restrict__ df)
{
    __shared__ float wf_s[H][64];
    __shared__ float e_s[32][H+4];
    __shared__ int   eidx_s[32];
    __shared__ int   snd_s[32];
    __shared__ int   rcv_s[32];
    __shared__ float dij_s[32][LD];

    const int tid = threadIdx.x;
    const int by  = blockIdx.y;          // column half [by*64, by*64+64)
    const int p0  = blockIdx.x * 32;     // sorted positions [p0, p0+32)

    if (tid < 32) eidx_s[tid] = eidx[p0 + tid];
    __syncthreads();
    if (tid < 32){ int e = eidx_s[tid]; snd_s[tid] = snd[e]; rcv_s[tid] = rcv[e]; }
    for (int i = tid; i < 32*LD; i += 256){
        int row = i >> 3, l = i & 7;
        dij_s[row][l] = dij[(size_t)eidx_s[row]*LD + l];
    }
    for (int i = tid; i < H*16; i += 256){           // Wf half: 128 x 16 f4
        int row = i >> 4, c4 = i & 15;
        *(float4*)&wf_s[row][c4*4] = *(const float4*)&Wf[row*H + by*64 + c4*4];
    }
    for (int i = tid; i < 32*32; i += 256){          // 32 rows x 32 f4
        int row = i >> 5, c4 = i & 31;
        *(float4*)&e_s[row][c4*4] = *(const float4*)&ef[(size_t)eidx_s[row]*H + c4*4];
    }
    __syncthreads();

    const int g = tid & 15, r0 = tid >> 4;           // 16 col-groups x 16 rows
    #pragma unroll
    for (int pass = 0; pass < 2; pass++){
        const int rr = r0 + pass*16;
        float4 af = f4z();
        for (int kk4 = 0; kk4 < H/4; kk4++){
            float4 e4 = *(const float4*)&e_s[rr][kk4*4];
            fma4(af, e4.x, *(float4*)&wf_s[kk4*4+0][g*4]);
            fma4(af, e4.y, *(float4*)&wf_s[kk4*4+1][g*4]);
            fma4(af, e4.z, *(float4*)&wf_s[kk4*4+2][g*4]);
            fma4(af, e4.w, *(float4*)&wf_s[kk4*4+3][g*4]);
        }
        float4 bf4 = *(const float4*)&bf_[by*64 + g*4];
        float4 f4v = silu4(af, bf4);

        const int e = eidx_s[rr];
        const int s = snd_s[rr], rn = rcv_s[rr];
        const ushort_t* Ar = Vt + (size_t)rn*LD*H + by*64 + g*4;
        const ushort_t* Br = Vs + (size_t)s*LD*H + by*64 + g*4;

        float4 AB = f4z(), aa = f4z(), bb = f4z();
        float dd = 0.f;
        #pragma unroll
        for (int l = 0; l < LD; l++){
            float dl = dij_s[rr][l];
            dd = fmaf(dl, dl, dd);
            uint2 ua = *(const uint2*)&Ar[(size_t)l*H];
            uint2 ub = *(const uint2*)&Br[(size_t)l*H];
            float Ax = bf2f_lo(ua.x), Ay = bf2f_hi(ua.x), Az = bf2f_lo(ua.y), Aw = bf2f_hi(ua.y);
            float Bx = bf2f_lo(ub.x), By = bf2f_hi(ub.x), Bz = bf2f_lo(ub.y), Bw = bf2f_hi(ub.y);
            AB.x = fmaf(Ax, Bx, AB.x); AB.y = fmaf(Ay, By, AB.y);
            AB.z = fmaf(Az, Bz, AB.z); AB.w = fmaf(Aw, Bw, AB.w);
            aa.x = fmaf(Ax, dl, aa.x); aa.y = fmaf(Ay, dl, aa.y);
            aa.z = fmaf(Az, dl, aa.z); aa.w = fmaf(Aw, dl, aa.w);
            bb.x = fmaf(Bx, dl, bb.x); bb.y = fmaf(By, dl, bb.y);
            bb.z = fmaf(Bz, dl, bb.z); bb.w = fmaf(Bw, dl, bb.w);
        }
        float c = 2.0f - dd;
        float4 o = make_float4(f4v.x*(AB.x - aa.x*bb.x*c),
                               f4v.y*(AB.y - aa.y*bb.y*c),
                               f4v.z*(AB.z - aa.z*bb.z*c),
                               f4v.w*(AB.w - aa.w*bb.w*c));
        *(float4*)&df[(size_t)e*H + by*64 + g*4] = o;
    }
}

// ---------------------------------------------------------------------------
// K5: per-receiver gather + fused node_post. 512 threads: four interleaved
// edge streams per node; Wo GEMV columns distributed across sub-groups.
// ---------------------------------------------------------------------------
__global__ __launch_bounds__(512) void node_gather(
    const int* __restrict__ offs, const int* __restrict__ eidx, const int* __restrict__ snd,
    const ushort_t* __restrict__ vj, const ushort_t* __restrict__ s12,
    const float* __restrict__ dij, const ushort_t* __restrict__ vec,
    const float* __restrict__ Wo, const float* __restrict__ bo,
    const float* __restrict__ vdot, const ushort_t* __restrict__ vec3,
    float* __restrict__ dx, float* __restrict__ dvec)
{
    const int n = blockIdx.x;
    const int tid = threadIdx.x;
    const int h = tid & 127;
    const int par = tid >> 7;            // 4 streams
    const int beg = offs[n], end = offs[n+1];
    float na = 0.f;
    float av[LD];
    #pragma unroll
    for (int l = 0; l < LD; l++) av[l] = 0.f;

    for (int i = beg + par; i < end; i += 4){
        int e = eidx[i];
        int s = snd[e];
        float vjv = bf2f_lo((unsigned int)vj[(size_t)e*H + h]);
        float s1 = bf2f_lo((unsigned int)s12[(size_t)e*256 + h]);
        float s2 = bf2f_lo((unsigned int)s12[(size_t)e*256 + 128 + h]);
        na += vjv;
        float4 d0 = *(const float4*)&dij[(size_t)e*LD];
        float4 d1 = *(const float4*)&dij[(size_t)e*LD + 4];
        const ushort_t* vr = &vec[(size_t)s*LD*H + h];
        av[0] = fmaf(bf2f_lo((unsigned int)vr[0*H]), s1, fmaf(d0.x, s2, av[0]));
        av[1] = fmaf(bf2f_lo((unsigned int)vr[1*H]), s1, fmaf(d0.y, s2, av[1]));
        av[2] = fmaf(bf2f_lo((unsigned int)vr[2*H]), s1, fmaf(d0.z, s2, av[2]));
        av[3] = fmaf(bf2f_lo((unsigned int)vr[3*H]), s1, fmaf(d0.w, s2, av[3]));
        av[4] = fmaf(bf2f_lo((unsigned int)vr[4*H]), s1, fmaf(d1.x, s2, av[4]));
        av[5] = fmaf(bf2f_lo((unsigned int)vr[5*H]), s1, fmaf(d1.y, s2, av[5]));
        av[6] = fmaf(bf2f_lo((unsigned int)vr[6*H]), s1, fmaf(d1.z, s2, av[6]));
        av[7] = fmaf(bf2f_lo((unsigned int)vr[7*H]), s1, fmaf(d1.w, s2, av[7]));
    }

    __shared__ float pl[4][LD+1][128];
    __shared__ float o_s[3][128];
    #pragma unroll
    for (int l = 0; l < LD; l++) pl[par][l][h] = av[l];
    pl[par][LD][h] = na;
    __syncthreads();

    if (par == 0){
        #pragma unroll
        for (int l = 0; l <= LD; l++)
            pl[0][l][h] = (pl[0][l][h] + pl[1][l][h]) + (pl[2][l][h] + pl[3][l][h]);
    }
    __syncthreads();

    if (par > 0){
        const int g = par - 1;                       // 0:o1, 1:o2, 2:o3
        float o = bo[g*H + h];
        for (int kk = 0; kk < H; kk++)
            o = fmaf(pl[0][LD][kk], Wo[kk*(3*H) + g*H + h], o);
        o_s[g][h] = o;
    }
    __syncthreads();

    if (par == 0){
        dx[(size_t)n*H + h] = fmaf(vdot[(size_t)n*H + h], o_s[1][h], o_s[2][h]);
        #pragma unroll
        for (int l = 0; l < LD; l++){
            size_t i2 = ((size_t)n*LD + l)*H + h;
            dvec[i2] = fmaf(bf2f_lo((unsigned int)vec3[i2]), o_s[0][h], pl[0][l][h]);
        }
    }
}

// ---------------------------------------------------------------------------
extern "C" void kernel_launch(void* const* d_in, const int* in_sizes, int n_in,
                              void* d_out, int out_size, void* d_ws, size_t ws_size,
                              hipStream_t stream) {
    const float* nf    = (const float*)d_in[0];
    const float* ef    = (const float*)d_in[1];
    const float* vf    = (const float*)d_in[2];
    const float* dist  = (const float*)d_in[3];
    const float* dij   = (const float*)d_in[4];
    const int*   snd   = (const int*)d_in[5];
    const int*   rcv   = (const int*)d_in[6];
    const float* ln_s  = (const float*)d_in[7];
    const float* ln_b  = (const float*)d_in[8];
    const float* vlnw  = (const float*)d_in[9];
    const float* W_vec = (const float*)d_in[10];
    const float* Wq    = (const float*)d_in[11];
    const float* bq    = (const float*)d_in[12];
    const float* Wk    = (const float*)d_in[13];
    const float* bk    = (const float*)d_in[14];
    const float* Wv    = (const float*)d_in[15];
    const float* bv    = (const float*)d_in[16];
    const float* Wdk   = (const float*)d_in[17];
    const float* bdk   = (const float*)d_in[18];
    const float* Wdv   = (const float*)d_in[19];
    const float* bdv   = (const float*)d_in[20];
    const float* Ws    = (const float*)d_in[21];
    const float* bs    = (const float*)d_in[22];
    const float* Wo    = (const float*)d_in[23];
    const float* bo    = (const float*)d_in[24];
    const float* Wf    = (const float*)d_in[25];
    const float* bf_   = (const float*)d_in[26];
    const float* Wsrc  = (const float*)d_in[27];
    const float* Wtrg  = (const float*)d_in[28];

    float* out  = (float*)d_out;
    float* dx   = out;                                  // [NN, H]
    float* df   = out + (size_t)NN*H;                   // [NE, H]
    float* dvec = df + (size_t)NE*H;                    // [NN, LD, H]

    float* w = (float*)d_ws;
    size_t off = 0;
    float* q    = w + off; off += (size_t)NN*H;
    float* vdot = w + off; off += (size_t)NN*H;
    ushort_t* k_bf   = (ushort_t*)(w + off); off += (size_t)NN*H/2;
    ushort_t* v_bf   = (ushort_t*)(w + off); off += (size_t)NN*H/2;
    ushort_t* x_bf   = (ushort_t*)(w + off); off += (size_t)NN*H/2;
    ushort_t* vec_bf = (ushort_t*)(w + off); off += (size_t)NN*LD*H/2;
    ushort_t* vec3   = (ushort_t*)(w + off); off += (size_t)NN*LD*H/2;
    ushort_t* Vt     = (ushort_t*)(w + off); off += (size_t)NN*LD*H/2;
    ushort_t* Vs     = (ushort_t*)(w + off); off += (size_t)NN*LD*H/2;
    ushort_t* vj     = (ushort_t*)(w + off); off += (size_t)NE*H/2;
    // s12 [E,256] bf16 aliases ef_bf [E,128] bf16 (ef_bf dead after edge_attn;
    // edge_s writes s12 afterwards).
    ushort_t* s12    = (ushort_t*)(w + off); off += (size_t)NE*256/2;
    ushort_t* ef_bf  = s12;
    ushort_t* wqkvT = (ushort_t*)(w + off); off += 384*128/2;
    ushort_t* wvecT = (ushort_t*)(w + off); off += 640*128/2;
    ushort_t* wdkT  = (ushort_t*)(w + off); off += 128*128/2;
    ushort_t* wdvT  = (ushort_t*)(w + off); off += 128*128/2;
    ushort_t* wsT   = (ushort_t*)(w + off); off += 256*128/2;
    int* cnt  = (int*)(w + off); off += NN;
    int* cnt2 = (int*)(w + off); off += NN;
    int* offs = (int*)(w + off); off += NN + 1;
    int* eidx = (int*)(w + off); off += NE;

    hipMemsetAsync(cnt,  0, NN*sizeof(int), stream);
    hipMemsetAsync(cnt2, 0, NN*sizeof(int), stream);

    k_prepw<<<768, 256, 0, stream>>>(Wq, Wk, Wv, W_vec, Wtrg, Wsrc, Wdk, Wdv, Ws,
                                     wqkvT, wvecT, wdkT, wdvT, wsT);
    k_ef2bf<<<NE*H/8/256, 256, 0, stream>>>(ef, ef_bf);

    k_hist<<<(NE+255)/256, 256, 0, stream>>>(rcv, cnt);
    k_scan<<<1, 256, 0, stream>>>(cnt, offs);
    k_scatter<<<(NE+255)/256, 256, 0, stream>>>(rcv, offs, cnt2, eidx);

    node_ln<<<NN, 128, 0, stream>>>(nf, vf, ln_s, ln_b, vlnw, x_bf, vec_bf);

    node_qkv<<<(NN+63)/64, 256, 0, stream>>>(x_bf, wqkvT, bq, bk, bv, q, k_bf, v_bf);

    node_vec<<<NN*LD/64, 256, 0, stream>>>(vec_bf, wvecT, vdot, vec3, Vt, Vs);

    edge_attn<<<NE/64, 256, 0, stream>>>(ef_bf, wdkT, bdk, wdvT, bdv, snd, rcv, dist,
                                         q, k_bf, v_bf, vj);

    edge_df<<<dim3(NE/32, 2), 256, 0, stream>>>(ef, Wf, bf_, eidx, snd, rcv, dij,
                                                Vt, Vs, df);

    edge_s<<<NE/64, 256, 0, stream>>>(vj, wsT, bs, s12);

    node_gather<<<NN, 512, 0, stream>>>(offs, eidx, snd, vj, s12, dij, vec_bf,
                                        Wo, bo, vdot, vec3, dx, dvec);
}

// Round 18
// 807.954 us; speedup vs baseline: 2.1776x; 2.1776x over previous
//
#include <hip/hip_runtime.h>
#include <math.h>

#define NN 10000
#define NE 160000
#define H  128
#define LD 8

typedef unsigned short ushort_t;
typedef short bf16x8 __attribute__((ext_vector_type(8)));
typedef float f32x4 __attribute__((ext_vector_type(4)));

__device__ __forceinline__ float silu_f(float x){ return x / (1.0f + expf(-x)); }
__device__ __forceinline__ float4 f4z(){ return make_float4(0.f,0.f,0.f,0.f); }

__device__ __forceinline__ void fma4(float4& acc, float s, const float4 w){
    acc.x = fmaf(s, w.x, acc.x);
    acc.y = fmaf(s, w.y, acc.y);
    acc.z = fmaf(s, w.z, acc.z);
    acc.w = fmaf(s, w.w, acc.w);
}

__device__ __forceinline__ float4 silu4(float4 a, float4 b){
    return make_float4(silu_f(a.x+b.x), silu_f(a.y+b.y), silu_f(a.z+b.z), silu_f(a.w+b.w));
}

__device__ __forceinline__ ushort_t f2bf(float f){
    union { float f; unsigned int u; } x; x.f = f;
    unsigned int r = x.u + 0x7FFFu + ((x.u >> 16) & 1u);
    return (ushort_t)(r >> 16);
}
__device__ __forceinline__ unsigned int pack2bf(float a, float b){
    return (unsigned int)f2bf(a) | ((unsigned int)f2bf(b) << 16);
}
__device__ __forceinline__ float bf2f_hi(unsigned int u){
    union { unsigned int u; float f; } x; x.u = u & 0xffff0000u; return x.f;
}
__device__ __forceinline__ float bf2f_lo(unsigned int u){
    union { unsigned int u; float f; } x; x.u = u << 16; return x.f;
}

// ---------------------------------------------------------------------------
// Prep: transpose GEMM weights to bf16 W^T[n][k]; cast ef to bf16.
// ---------------------------------------------------------------------------
__global__ void k_prepw(const float* __restrict__ Wq, const float* __restrict__ Wk,
                        const float* __restrict__ Wv, const float* __restrict__ W_vec,
                        const float* __restrict__ Wtrg, const float* __restrict__ Wsrc,
                        const float* __restrict__ Wdk, const float* __restrict__ Wdv,
                        const float* __restrict__ Ws,
                        ushort_t* __restrict__ wqkvT, ushort_t* __restrict__ wvecT,
                        ushort_t* __restrict__ wdkT, ushort_t* __restrict__ wdvT,
                        ushort_t* __restrict__ wsT){
    int i = blockIdx.x * 256 + threadIdx.x;          // 0 .. 196607
    int n = i >> 7, kk = i & 127;
    if (n < 384){                                    // wqkvT
        float v;
        if (n < 128)      v = Wq[kk*128 + n];
        else if (n < 256) v = Wk[kk*128 + (n-128)];
        else              v = Wv[kk*128 + (n-256)];
        wqkvT[n*128 + kk] = f2bf(v);
    } else if (n < 1024){                            // wvecT (640 rows)
        int m = n - 384;
        float v;
        if (m < 384)      v = W_vec[kk*384 + m];
        else if (m < 512) v = Wtrg[kk*128 + (m-384)];
        else              v = Wsrc[kk*128 + (m-512)];
        wvecT[m*128 + kk] = f2bf(v);
    } else if (n < 1152){
        int m = n - 1024;
        wdkT[m*128 + kk] = f2bf(Wdk[kk*128 + m]);
    } else if (n < 1280){
        int m = n - 1152;
        wdvT[m*128 + kk] = f2bf(Wdv[kk*128 + m]);
    } else if (n < 1536){
        int m = n - 1280;
        wsT[m*128 + kk] = f2bf(Ws[kk*256 + m]);
    }
}

__global__ void k_ef2bf(const float* __restrict__ ef, ushort_t* __restrict__ ef_bf){
    size_t i = (size_t)blockIdx.x * 256 + threadIdx.x;   // over E*H/8
    const float4* s = (const float4*)ef;
    float4 a = s[2*i], b = s[2*i+1];
    uint4 u;
    u.x = pack2bf(a.x, a.y); u.y = pack2bf(a.z, a.w);
    u.z = pack2bf(b.x, b.y); u.w = pack2bf(b.z, b.w);
    ((uint4*)ef_bf)[i] = u;
}

// ---------------------------------------------------------------------------
// Sort edges by receiver: histogram -> exclusive scan -> rank scatter.
// ---------------------------------------------------------------------------
__global__ void k_hist(const int* __restrict__ rcv, int* __restrict__ cnt){
    int e = blockIdx.x * 256 + threadIdx.x;
    if (e < NE) atomicAdd(&cnt[rcv[e]], 1);
}

__global__ __launch_bounds__(256) void k_scan(const int* __restrict__ cnt, int* __restrict__ offs){
    __shared__ int part[256];
    const int t = threadIdx.x;
    const int CH = 40;
    int loc[CH];
    int base = t * CH;
    int lsum = 0;
    if (base < NN){
        #pragma unroll
        for (int i = 0; i < CH; i++){ loc[i] = cnt[base + i]; lsum += loc[i]; }
    }
    part[t] = lsum;
    __syncthreads();
    for (int off = 1; off < 256; off <<= 1){
        int v = (t >= off) ? part[t - off] : 0;
        __syncthreads();
        part[t] += v;
        __syncthreads();
    }
    int ex = part[t] - lsum;
    if (base < NN){
        int run = ex;
        #pragma unroll
        for (int i = 0; i < CH; i++){ offs[base + i] = run; run += loc[i]; }
    }
    if (t == 255) offs[NN] = part[255];
}

__global__ void k_scatter(const int* __restrict__ rcv, const int* __restrict__ offs,
                          int* __restrict__ cnt2, int* __restrict__ eidx){
    int e = blockIdx.x * 256 + threadIdx.x;
    if (e < NE){
        int r = rcv[e];
        int p = atomicAdd(&cnt2[r], 1);
        eidx[offs[r] + p] = e;
    }
}

// ---------------------------------------------------------------------------
// K1a: LayerNorm -> x_bf (bf16); vec = vf*vln_w -> vec_bf (bf16).
// ---------------------------------------------------------------------------
__global__ __launch_bounds__(128) void node_ln(
    const float* __restrict__ nf, const float* __restrict__ vf,
    const float* __restrict__ ln_s, const float* __restrict__ ln_b,
    const float* __restrict__ vlnw,
    ushort_t* __restrict__ x_bf, ushort_t* __restrict__ vec_bf)
{
    const int n = blockIdx.x, h = threadIdx.x;
    __shared__ float red[4];
    float xv = nf[(size_t)n*H + h];
    float s1 = xv, s2 = xv*xv;
    #pragma unroll
    for (int o = 32; o >= 1; o >>= 1){
        s1 += __shfl_xor(s1, o, 64);
        s2 += __shfl_xor(s2, o, 64);
    }
    const int wid = h >> 6;
    if ((h & 63) == 0){ red[wid] = s1; red[2+wid] = s2; }
    __syncthreads();
    float mean = (red[0] + red[1]) * (1.0f/H);
    float var  = (red[2] + red[3]) * (1.0f/H) - mean*mean;
    float x = (xv - mean) * rsqrtf(var + 1e-5f) * ln_s[h] + ln_b[h];
    x_bf[(size_t)n*H + h] = f2bf(x);
    float w = vlnw[h];
    #pragma unroll
    for (int l = 0; l < LD; l++){
        size_t i = ((size_t)n*LD + l)*H + h;
        vec_bf[i] = f2bf(vf[i] * w);
    }
}

// ---------------------------------------------------------------------------
// K1b (MFMA): q (f32), k/v (bf16) = x_bf @ wqkvT^T + bias.
// ---------------------------------------------------------------------------
__global__ __launch_bounds__(256) void node_qkv(
    const ushort_t* __restrict__ x_bf, const ushort_t* __restrict__ wqkvT,
    const float* __restrict__ bq, const float* __restrict__ bk, const float* __restrict__ bv,
    float* __restrict__ q, ushort_t* __restrict__ k_bf, ushort_t* __restrict__ v_bf)
{
    const int tid  = threadIdx.x;
    const int lane = tid & 63;
    const int m0   = (tid >> 6) * 16;
    const int e0   = blockIdx.x * 64;

    const int mrow = lane & 15;
    const int kblk = lane >> 4;

    f32x4 acc[24];
    #pragma unroll
    for (int nt = 0; nt < 24; nt++) acc[nt] = (f32x4)(0.f);

    int arow = e0 + m0 + mrow; if (arow >= NN) arow = NN-1;
    const ushort_t* Arow = x_bf + (size_t)arow*H + kblk*8;
    const ushort_t* wb   = wqkvT + (size_t)mrow*H + kblk*8;

    #pragma unroll
    for (int ks = 0; ks < 4; ks++){
        bf16x8 a = *(const bf16x8*)(Arow + ks*32);
        #pragma unroll
        for (int nt = 0; nt < 24; nt++){
            bf16x8 b8 = *(const bf16x8*)(wb + (size_t)nt*16*H + ks*32);
            acc[nt] = __builtin_amdgcn_mfma_f32_16x16x32_bf16(a, b8, acc[nt], 0, 0, 0);
        }
    }
    #pragma unroll
    for (int t = 0; t < 8; t++){
        int col = t*16 + mrow;
        float bb = bq[col];
        #pragma unroll
        for (int r = 0; r < 4; r++){
            int row = e0 + m0 + kblk*4 + r;
            if (row < NN) q[(size_t)row*H + col] = acc[t][r] + bb;
        }
    }
    #pragma unroll
    for (int t = 0; t < 8; t++){
        int col = t*16 + mrow;
        float bb = bk[col];
        #pragma unroll
        for (int r = 0; r < 4; r++){
            int row = e0 + m0 + kblk*4 + r;
            if (row < NN) k_bf[(size_t)row*H + col] = f2bf(acc[8+t][r] + bb);
        }
    }
    #pragma unroll
    for (int t = 0; t < 8; t++){
        int col = t*16 + mrow;
        float bb = bv[col];
        #pragma unroll
        for (int r = 0; r < 4; r++){
            int row = e0 + m0 + kblk*4 + r;
            if (row < NN) v_bf[(size_t)row*H + col] = f2bf(acc[16+t][r] + bb);
        }
    }
}

// ---------------------------------------------------------------------------
// K1c (MFMA): V5 = vec_bf @ wvecT^T, N=640; fused vdot + bf16 outputs
// (vec3 / Vt / Vs in row layout).
// ---------------------------------------------------------------------------
__global__ __launch_bounds__(256) void node_vec(
    const ushort_t* __restrict__ vec_bf, const ushort_t* __restrict__ wvecT,
    float* __restrict__ vdot, ushort_t* __restrict__ vec3,
    ushort_t* __restrict__ Vt, ushort_t* __restrict__ Vs)
{
    __shared__ ushort_t st_s[64][136];

    const int tid  = threadIdx.x;
    const int lane = tid & 63;
    const int wv   = tid >> 6;
    const int m0   = wv * 16;
    const size_t r0 = (size_t)blockIdx.x * 64;       // global row = node*8+l

    const int mrow = lane & 15;
    const int kblk = lane >> 4;

    f32x4 acc[40];
    #pragma unroll
    for (int nt = 0; nt < 40; nt++) acc[nt] = (f32x4)(0.f);

    const ushort_t* Arow = vec_bf + (r0 + m0 + mrow)*H + kblk*8;
    const ushort_t* wb   = wvecT + (size_t)mrow*H + kblk*8;

    #pragma unroll
    for (int ks = 0; ks < 4; ks++){
        bf16x8 a = *(const bf16x8*)(Arow + ks*32);
        #pragma unroll
        for (int nt = 0; nt < 40; nt++){
            bf16x8 b8 = *(const bf16x8*)(wb + (size_t)nt*16*H + ks*32);
            acc[nt] = __builtin_amdgcn_mfma_f32_16x16x32_bf16(a, b8, acc[nt], 0, 0, 0);
        }
    }

    #pragma unroll
    for (int t = 0; t < 8; t++){
        float p = acc[t][0]*acc[t+8][0] + acc[t][1]*acc[t+8][1]
                + acc[t][2]*acc[t+8][2] + acc[t][3]*acc[t+8][3];
        p += __shfl_xor(p, 16, 64);                  // kblk 0<->1, 2<->3
        if ((kblk & 1) == 0){
            int node = (int)(r0 >> 3) + wv*2 + (kblk >> 1);
            vdot[(size_t)node*H + t*16 + mrow] = p;
        }
    }

    ushort_t* outs[3] = {vec3, Vt, Vs};
    #pragma unroll
    for (int g = 0; g < 3; g++){
        __syncthreads();
        #pragma unroll
        for (int t = 0; t < 8; t++){
            int coln = t*16 + mrow;
            int lr = m0 + kblk*4;
            st_s[lr+0][coln] = f2bf(acc[16+g*8+t][0]);
            st_s[lr+1][coln] = f2bf(acc[16+g*8+t][1]);
            st_s[lr+2][coln] = f2bf(acc[16+g*8+t][2]);
            st_s[lr+3][coln] = f2bf(acc[16+g*8+t][3]);
        }
        __syncthreads();
        const int rr = tid >> 2, qq = tid & 3;
        uint4* dst = (uint4*)&outs[g][(r0 + rr)*H + qq*32];
        const uint4* src = (const uint4*)&st_s[rr][qq*32];
        dst[0] = src[0]; dst[1] = src[1]; dst[2] = src[2]; dst[3] = src[3];
    }
}

// ---------------------------------------------------------------------------
// K2 (MFMA): dk/dv = silu(ef@Wdk/dv + b), attention epilogue -> vj (bf16).
// Natural edge order; k/v gathered as bf16 (halved bytes).
// ---------------------------------------------------------------------------
__global__ __launch_bounds__(256) void edge_attn(
    const ushort_t* __restrict__ ef_bf,
    const ushort_t* __restrict__ wdkT, const float* __restrict__ bdk,
    const ushort_t* __restrict__ wdvT, const float* __restrict__ bdv,
    const int* __restrict__ snd, const int* __restrict__ rcv,
    const float* __restrict__ dist,
    const float* __restrict__ q, const ushort_t* __restrict__ k_bf,
    const ushort_t* __restrict__ v_bf,
    ushort_t* __restrict__ vj)
{
    __shared__ ushort_t dk_s[64][136];
    __shared__ ushort_t dv_s[64][136];

    const int tid  = threadIdx.x;
    const int lane = tid & 63;
    const int m0   = (tid >> 6) * 16;
    const size_t e0 = (size_t)blockIdx.x * 64;

    const int mrow = lane & 15;
    const int kblk = lane >> 4;

    f32x4 accK[8], accV[8];
    #pragma unroll
    for (int nt = 0; nt < 8; nt++){ accK[nt] = (f32x4)(0.f); accV[nt] = (f32x4)(0.f); }

    const ushort_t* Arow = ef_bf + (e0 + m0 + mrow)*H + kblk*8;
    const ushort_t* wkb  = wdkT + (size_t)mrow*H + kblk*8;
    const ushort_t* wvb  = wdvT + (size_t)mrow*H + kblk*8;

    #pragma unroll
    for (int ks = 0; ks < 4; ks++){
        bf16x8 a = *(const bf16x8*)(Arow + ks*32);
        #pragma unroll
        for (int nt = 0; nt < 8; nt++){
            bf16x8 bk8 = *(const bf16x8*)(wkb + (size_t)nt*16*H + ks*32);
            accK[nt] = __builtin_amdgcn_mfma_f32_16x16x32_bf16(a, bk8, accK[nt], 0, 0, 0);
            bf16x8 bv8 = *(const bf16x8*)(wvb + (size_t)nt*16*H + ks*32);
            accV[nt] = __builtin_amdgcn_mfma_f32_16x16x32_bf16(a, bv8, accV[nt], 0, 0, 0);
        }
    }

    const int lrow = m0 + 4*kblk;
    #pragma unroll
    for (int nt = 0; nt < 8; nt++){
        int coln = nt*16 + mrow;
        float bkn = bdk[coln], bvn = bdv[coln];
        #pragma unroll
        for (int r = 0; r < 4; r++){
            dk_s[lrow + r][coln] = f2bf(silu_f(accK[nt][r] + bkn));
            dv_s[lrow + r][coln] = f2bf(silu_f(accV[nt][r] + bvn));
        }
    }
    __syncthreads();

    const int r  = tid >> 2, cq = tid & 3;
    const size_t e = e0 + r;
    const int s  = snd[e], rr = rcv[e];
    const float d = dist[e];
    const float cut = (d < 5.0f) ? 0.5f*(cosf(d*0.6283185307179586f) + 1.0f) : 0.0f;
    const float*    qrow = q    + (size_t)rr*H + cq*32;
    const ushort_t* krow = k_bf + (size_t)s*H + cq*32;
    const ushort_t* vrow = v_bf + (size_t)s*H + cq*32;
    ushort_t* vjrow = vj + e*H + cq*32;

    #pragma unroll
    for (int hh = 0; hh < 2; hh++){
        const int c0 = hh*16;
        float p = 0.f;
        #pragma unroll
        for (int j = 0; j < 4; j++){
            float4 q4 = *(const float4*)(qrow + c0 + 4*j);
            uint2 ku = *(const uint2*)(krow + c0 + 4*j);
            uint2 du = *(const uint2*)&dk_s[r][cq*32 + c0 + 4*j];
            p += q4.x*bf2f_lo(ku.x)*bf2f_lo(du.x) + q4.y*bf2f_hi(ku.x)*bf2f_hi(du.x)
               + q4.z*bf2f_lo(ku.y)*bf2f_lo(du.y) + q4.w*bf2f_hi(ku.y)*bf2f_hi(du.y);
        }
        float attn = silu_f(p) * cut;
        #pragma unroll
        for (int j = 0; j < 4; j++){
            uint2 vu = *(const uint2*)(vrow + c0 + 4*j);
            uint2 du = *(const uint2*)&dv_s[r][cq*32 + c0 + 4*j];
            uint2 u;
            u.x = pack2bf(bf2f_lo(vu.x)*bf2f_lo(du.x)*attn,
                          bf2f_hi(vu.x)*bf2f_hi(du.x)*attn);
            u.y = pack2bf(bf2f_lo(vu.y)*bf2f_lo(du.y)*attn,
                          bf2f_hi(vu.y)*bf2f_hi(du.y)*attn);
            *(uint2*)(vjrow + c0 + 4*j) = u;
        }
    }
}

// ---------------------------------------------------------------------------
// K3 (MFMA): s12 = silu(vj@Ws + bs) [E,256] bf16.
// ---------------------------------------------------------------------------
__global__ __launch_bounds__(256) void edge_s(
    const ushort_t* __restrict__ vj, const ushort_t* __restrict__ wsT,
    const float* __restrict__ bs, ushort_t* __restrict__ s12)
{
    __shared__ ushort_t s_s[64][264];

    const int tid  = threadIdx.x;
    const int lane = tid & 63;
    const int m0   = (tid >> 6) * 16;
    const size_t e0 = (size_t)blockIdx.x * 64;

    const int mrow = lane & 15;
    const int kblk = lane >> 4;

    f32x4 acc[16];
    #pragma unroll
    for (int nt = 0; nt < 16; nt++) acc[nt] = (f32x4)(0.f);

    const ushort_t* Arow = vj + (e0 + m0 + mrow)*H + kblk*8;
    const ushort_t* wb   = wsT + (size_t)mrow*H + kblk*8;

    #pragma unroll
    for (int ks = 0; ks < 4; ks++){
        bf16x8 a = *(const bf16x8*)(Arow + ks*32);
        #pragma unroll
        for (int nt = 0; nt < 16; nt++){
            bf16x8 b8 = *(const bf16x8*)(wb + (size_t)nt*16*H + ks*32);
            acc[nt] = __builtin_amdgcn_mfma_f32_16x16x32_bf16(a, b8, acc[nt], 0, 0, 0);
        }
    }

    const int lrow = m0 + 4*kblk;
    #pragma unroll
    for (int nt = 0; nt < 16; nt++){
        int coln = nt*16 + mrow;
        float bb = bs[coln];
        #pragma unroll
        for (int r = 0; r < 4; r++)
            s_s[lrow + r][coln] = f2bf(silu_f(acc[nt][r] + bb));
    }
    __syncthreads();

    const int r = tid >> 2, cq = tid & 3;
    const uint4* srcp = (const uint4*)&s_s[r][cq*64];
    uint4* dstp = (uint4*)&s12[(e0 + r)*256 + cq*64];
    #pragma unroll
    for (int j = 0; j < 8; j++) dstp[j] = srcp[j];
}

// ---------------------------------------------------------------------------
// K4 (f32 GEMV — proven-precision path): df = silu(ef@Wf+bf) * w_dot with
// w_dot = (A.B) - a*b*(2-|d|^2), A=Vt[rcv], B=Vs[snd] (bf16).
// 32 edges/block, column-HALF per blockIdx.y. LDS ~51KB -> 3 blocks/CU.
// Scalar e_s reads (r17's float4 variant spilled: VGPR 256, 6x regression).
// Receiver-sorted edge order.
// ---------------------------------------------------------------------------
__global__ __launch_bounds__(256) void edge_df(
    const float* __restrict__ ef, const float* __restrict__ Wf, const float* __restrict__ bf_,
    const int* __restrict__ eidx,
    const int* __restrict__ snd, const int* __restrict__ rcv,
    const float* __restrict__ dij,
    const ushort_t* __restrict__ Vt, const ushort_t* __restrict__ Vs,
    float* __restrict__ df)
{
    __shared__ float wf_s[H][64];
    __shared__ float e_s[32][H+4];
    __shared__ int   eidx_s[32];
    __shared__ int   snd_s[32];
    __shared__ int   rcv_s[32];
    __shared__ float dij_s[32][LD];

    const int tid = threadIdx.x;
    const int by  = blockIdx.y;          // column half [by*64, by*64+64)
    const int p0  = blockIdx.x * 32;     // sorted positions [p0, p0+32)

    if (tid < 32) eidx_s[tid] = eidx[p0 + tid];
    __syncthreads();
    if (tid < 32){ int e = eidx_s[tid]; snd_s[tid] = snd[e]; rcv_s[tid] = rcv[e]; }
    for (int i = tid; i < 32*LD; i += 256){
        int row = i >> 3, l = i & 7;
        dij_s[row][l] = dij[(size_t)eidx_s[row]*LD + l];
    }
    for (int i = tid; i < H*16; i += 256){           // Wf half: 128 x 16 f4
        int row = i >> 4, c4 = i & 15;
        *(float4*)&wf_s[row][c4*4] = *(const float4*)&Wf[row*H + by*64 + c4*4];
    }
    for (int i = tid; i < 32*32; i += 256){          // 32 rows x 32 f4
        int row = i >> 5, c4 = i & 31;
        *(float4*)&e_s[row][c4*4] = *(const float4*)&ef[(size_t)eidx_s[row]*H + c4*4];
    }
    __syncthreads();

    const int g = tid & 15, r0 = tid >> 4;           // 16 col-groups x 16 rows
    #pragma unroll
    for (int pass = 0; pass < 2; pass++){
        const int rr = r0 + pass*16;
        float4 af = f4z();
        for (int kk = 0; kk < H; kk++){
            float4 w4 = *(float4*)&wf_s[kk][g*4];
            fma4(af, e_s[rr][kk], w4);
        }
        float4 bf4 = *(const float4*)&bf_[by*64 + g*4];
        float4 f4v = silu4(af, bf4);

        const int e = eidx_s[rr];
        const int s = snd_s[rr], rn = rcv_s[rr];
        const ushort_t* Ar = Vt + (size_t)rn*LD*H + by*64 + g*4;
        const ushort_t* Br = Vs + (size_t)s*LD*H + by*64 + g*4;

        float4 AB = f4z(), aa = f4z(), bb = f4z();
        float dd = 0.f;
        #pragma unroll
        for (int l = 0; l < LD; l++){
            float dl = dij_s[rr][l];
            dd = fmaf(dl, dl, dd);
            uint2 ua = *(const uint2*)&Ar[(size_t)l*H];
            uint2 ub = *(const uint2*)&Br[(size_t)l*H];
            float Ax = bf2f_lo(ua.x), Ay = bf2f_hi(ua.x), Az = bf2f_lo(ua.y), Aw = bf2f_hi(ua.y);
            float Bx = bf2f_lo(ub.x), By = bf2f_hi(ub.x), Bz = bf2f_lo(ub.y), Bw = bf2f_hi(ub.y);
            AB.x = fmaf(Ax, Bx, AB.x); AB.y = fmaf(Ay, By, AB.y);
            AB.z = fmaf(Az, Bz, AB.z); AB.w = fmaf(Aw, Bw, AB.w);
            aa.x = fmaf(Ax, dl, aa.x); aa.y = fmaf(Ay, dl, aa.y);
            aa.z = fmaf(Az, dl, aa.z); aa.w = fmaf(Aw, dl, aa.w);
            bb.x = fmaf(Bx, dl, bb.x); bb.y = fmaf(By, dl, bb.y);
            bb.z = fmaf(Bz, dl, bb.z); bb.w = fmaf(Bw, dl, bb.w);
        }
        float c = 2.0f - dd;
        float4 o = make_float4(f4v.x*(AB.x - aa.x*bb.x*c),
                               f4v.y*(AB.y - aa.y*bb.y*c),
                               f4v.z*(AB.z - aa.z*bb.z*c),
                               f4v.w*(AB.w - aa.w*bb.w*c));
        *(float4*)&df[(size_t)e*H + by*64 + g*4] = o;
    }
}

// ---------------------------------------------------------------------------
// K5: per-receiver gather + fused node_post. 512 threads: four interleaved
// edge streams per node; Wo GEMV columns distributed across sub-groups.
// ---------------------------------------------------------------------------
__global__ __launch_bounds__(512) void node_gather(
    const int* __restrict__ offs, const int* __restrict__ eidx, const int* __restrict__ snd,
    const ushort_t* __restrict__ vj, const ushort_t* __restrict__ s12,
    const float* __restrict__ dij, const ushort_t* __restrict__ vec,
    const float* __restrict__ Wo, const float* __restrict__ bo,
    const float* __restrict__ vdot, const ushort_t* __restrict__ vec3,
    float* __restrict__ dx, float* __restrict__ dvec)
{
    const int n = blockIdx.x;
    const int tid = threadIdx.x;
    const int h = tid & 127;
    const int par = tid >> 7;            // 4 streams
    const int beg = offs[n], end = offs[n+1];
    float na = 0.f;
    float av[LD];
    #pragma unroll
    for (int l = 0; l < LD; l++) av[l] = 0.f;

    for (int i = beg + par; i < end; i += 4){
        int e = eidx[i];
        int s = snd[e];
        float vjv = bf2f_lo((unsigned int)vj[(size_t)e*H + h]);
        float s1 = bf2f_lo((unsigned int)s12[(size_t)e*256 + h]);
        float s2 = bf2f_lo((unsigned int)s12[(size_t)e*256 + 128 + h]);
        na += vjv;
        float4 d0 = *(const float4*)&dij[(size_t)e*LD];
        float4 d1 = *(const float4*)&dij[(size_t)e*LD + 4];
        const ushort_t* vr = &vec[(size_t)s*LD*H + h];
        av[0] = fmaf(bf2f_lo((unsigned int)vr[0*H]), s1, fmaf(d0.x, s2, av[0]));
        av[1] = fmaf(bf2f_lo((unsigned int)vr[1*H]), s1, fmaf(d0.y, s2, av[1]));
        av[2] = fmaf(bf2f_lo((unsigned int)vr[2*H]), s1, fmaf(d0.z, s2, av[2]));
        av[3] = fmaf(bf2f_lo((unsigned int)vr[3*H]), s1, fmaf(d0.w, s2, av[3]));
        av[4] = fmaf(bf2f_lo((unsigned int)vr[4*H]), s1, fmaf(d1.x, s2, av[4]));
        av[5] = fmaf(bf2f_lo((unsigned int)vr[5*H]), s1, fmaf(d1.y, s2, av[5]));
        av[6] = fmaf(bf2f_lo((unsigned int)vr[6*H]), s1, fmaf(d1.z, s2, av[6]));
        av[7] = fmaf(bf2f_lo((unsigned int)vr[7*H]), s1, fmaf(d1.w, s2, av[7]));
    }

    __shared__ float pl[4][LD+1][128];
    __shared__ float o_s[3][128];
    #pragma unroll
    for (int l = 0; l < LD; l++) pl[par][l][h] = av[l];
    pl[par][LD][h] = na;
    __syncthreads();

    if (par == 0){
        #pragma unroll
        for (int l = 0; l <= LD; l++)
            pl[0][l][h] = (pl[0][l][h] + pl[1][l][h]) + (pl[2][l][h] + pl[3][l][h]);
    }
    __syncthreads();

    if (par > 0){
        const int g = par - 1;                       // 0:o1, 1:o2, 2:o3
        float o = bo[g*H + h];
        for (int kk = 0; kk < H; kk++)
            o = fmaf(pl[0][LD][kk], Wo[kk*(3*H) + g*H + h], o);
        o_s[g][h] = o;
    }
    __syncthreads();

    if (par == 0){
        dx[(size_t)n*H + h] = fmaf(vdot[(size_t)n*H + h], o_s[1][h], o_s[2][h]);
        #pragma unroll
        for (int l = 0; l < LD; l++){
            size_t i2 = ((size_t)n*LD + l)*H + h;
            dvec[i2] = fmaf(bf2f_lo((unsigned int)vec3[i2]), o_s[0][h], pl[0][l][h]);
        }
    }
}

// ---------------------------------------------------------------------------
extern "C" void kernel_launch(void* const* d_in, const int* in_sizes, int n_in,
                              void* d_out, int out_size, void* d_ws, size_t ws_size,
                              hipStream_t stream) {
    const float* nf    = (const float*)d_in[0];
    const float* ef    = (const float*)d_in[1];
    const float* vf    = (const float*)d_in[2];
    const float* dist  = (const float*)d_in[3];
    const float* dij   = (const float*)d_in[4];
    const int*   snd   = (const int*)d_in[5];
    const int*   rcv   = (const int*)d_in[6];
    const float* ln_s  = (const float*)d_in[7];
    const float* ln_b  = (const float*)d_in[8];
    const float* vlnw  = (const float*)d_in[9];
    const float* W_vec = (const float*)d_in[10];
    const float* Wq    = (const float*)d_in[11];
    const float* bq    = (const float*)d_in[12];
    const float* Wk    = (const float*)d_in[13];
    const float* bk    = (const float*)d_in[14];
    const float* Wv    = (const float*)d_in[15];
    const float* bv    = (const float*)d_in[16];
    const float* Wdk   = (const float*)d_in[17];
    const float* bdk   = (const float*)d_in[18];
    const float* Wdv   = (const float*)d_in[19];
    const float* bdv   = (const float*)d_in[20];
    const float* Ws    = (const float*)d_in[21];
    const float* bs    = (const float*)d_in[22];
    const float* Wo    = (const float*)d_in[23];
    const float* bo    = (const float*)d_in[24];
    const float* Wf    = (const float*)d_in[25];
    const float* bf_   = (const float*)d_in[26];
    const float* Wsrc  = (const float*)d_in[27];
    const float* Wtrg  = (const float*)d_in[28];

    float* out  = (float*)d_out;
    float* dx   = out;                                  // [NN, H]
    float* df   = out + (size_t)NN*H;                   // [NE, H]
    float* dvec = df + (size_t)NE*H;                    // [NN, LD, H]

    float* w = (float*)d_ws;
    size_t off = 0;
    float* q    = w + off; off += (size_t)NN*H;
    float* vdot = w + off; off += (size_t)NN*H;
    ushort_t* k_bf   = (ushort_t*)(w + off); off += (size_t)NN*H/2;
    ushort_t* v_bf   = (ushort_t*)(w + off); off += (size_t)NN*H/2;
    ushort_t* x_bf   = (ushort_t*)(w + off); off += (size_t)NN*H/2;
    ushort_t* vec_bf = (ushort_t*)(w + off); off += (size_t)NN*LD*H/2;
    ushort_t* vec3   = (ushort_t*)(w + off); off += (size_t)NN*LD*H/2;
    ushort_t* Vt     = (ushort_t*)(w + off); off += (size_t)NN*LD*H/2;
    ushort_t* Vs     = (ushort_t*)(w + off); off += (size_t)NN*LD*H/2;
    ushort_t* vj     = (ushort_t*)(w + off); off += (size_t)NE*H/2;
    // s12 [E,256] bf16 aliases ef_bf [E,128] bf16 (ef_bf dead after edge_attn;
    // edge_s writes s12 afterwards).
    ushort_t* s12    = (ushort_t*)(w + off); off += (size_t)NE*256/2;
    ushort_t* ef_bf  = s12;
    ushort_t* wqkvT = (ushort_t*)(w + off); off += 384*128/2;
    ushort_t* wvecT = (ushort_t*)(w + off); off += 640*128/2;
    ushort_t* wdkT  = (ushort_t*)(w + off); off += 128*128/2;
    ushort_t* wdvT  = (ushort_t*)(w + off); off += 128*128/2;
    ushort_t* wsT   = (ushort_t*)(w + off); off += 256*128/2;
    int* cnt  = (int*)(w + off); off += NN;
    int* cnt2 = (int*)(w + off); off += NN;
    int* offs = (int*)(w + off); off += NN + 1;
    int* eidx = (int*)(w + off); off += NE;

    hipMemsetAsync(cnt,  0, NN*sizeof(int), stream);
    hipMemsetAsync(cnt2, 0, NN*sizeof(int), stream);

    k_prepw<<<768, 256, 0, stream>>>(Wq, Wk, Wv, W_vec, Wtrg, Wsrc, Wdk, Wdv, Ws,
                                     wqkvT, wvecT, wdkT, wdvT, wsT);
    k_ef2bf<<<NE*H/8/256, 256, 0, stream>>>(ef, ef_bf);

    k_hist<<<(NE+255)/256, 256, 0, stream>>>(rcv, cnt);
    k_scan<<<1, 256, 0, stream>>>(cnt, offs);
    k_scatter<<<(NE+255)/256, 256, 0, stream>>>(rcv, offs, cnt2, eidx);

    node_ln<<<NN, 128, 0, stream>>>(nf, vf, ln_s, ln_b, vlnw, x_bf, vec_bf);

    node_qkv<<<(NN+63)/64, 256, 0, stream>>>(x_bf, wqkvT, bq, bk, bv, q, k_bf, v_bf);

    node_vec<<<NN*LD/64, 256, 0, stream>>>(vec_bf, wvecT, vdot, vec3, Vt, Vs);

    edge_attn<<<NE/64, 256, 0, stream>>>(ef_bf, wdkT, bdk, wdvT, bdv, snd, rcv, dist,
                                         q, k_bf, v_bf, vj);

    edge_df<<<dim3(NE/32, 2), 256, 0, stream>>>(ef, Wf, bf_, eidx, snd, rcv, dij,
                                                Vt, Vs, df);

    edge_s<<<NE/64, 256, 0, stream>>>(vj, wsT, bs, s12);

    node_gather<<<NN, 512, 0, stream>>>(offs, eidx, snd, vj, s12, dij, vec_bf,
                                        Wo, bo, vdot, vec3, dx, dvec);
}